// Round 1
// baseline (604.780 us; speedup 1.0000x reference)
//
#include <hip/hip_runtime.h>

#define BB   16    // batch
#define NW   32    // WORDS (output capsules)
#define DIMM 256   // DIM
#define DH   32    // DIM_HEAD
#define NI   256   // INNER
#define NJ   256   // J = WORDS*HEADS (input capsules)

// xi = x @ Wi^T + bi  -> stored as xh [B, NJ, DH] (identical flat layout)
__global__ void k_proj_in(const float* __restrict__ x, const float* __restrict__ Wi,
                          const float* __restrict__ bi, float* __restrict__ xh) {
    int row = blockIdx.x;          // b*NW + n  (512 rows)
    int k = threadIdx.x;           // 0..255
    __shared__ float xr[DIMM];
    xr[k] = x[(size_t)row * DIMM + k];
    __syncthreads();
    const float4* wi  = (const float4*)(Wi + (size_t)k * DIMM);
    const float4* xr4 = (const float4*)xr;
    float acc = bi[k];
#pragma unroll 8
    for (int m = 0; m < DIMM / 4; ++m) {
        float4 w = wi[m]; float4 xv = xr4[m];
        acc += w.x * xv.x + w.y * xv.y + w.z * xv.z + w.w * xv.w;
    }
    xh[(size_t)row * DIMM + k] = acc;
}

// u[b,j,i,e] = sum_d W[j,i,e,d] * xh[b,j,d] + bias[j,i,e]
// one block per (j,i); thread = e; loops over b with W row in registers
__global__ void k_uhat(const float* __restrict__ W, const float* __restrict__ bias,
                       const float* __restrict__ xh, float* __restrict__ u) {
    int j = blockIdx.x >> 5;
    int i = blockIdx.x & 31;
    int e = threadIdx.x;
    __shared__ float xs[BB][DH];
    for (int t = threadIdx.x; t < BB * DH; t += 256) {
        int b = t >> 5, d = t & 31;
        xs[b][d] = xh[((size_t)b * NJ + j) * DH + d];
    }
    __syncthreads();
    const float4* wp = (const float4*)(W + (((size_t)j * NW + i) * NI + e) * DH);
    float4 w4[8];
#pragma unroll
    for (int q = 0; q < 8; ++q) w4[q] = wp[q];
    const float* w = (const float*)w4;
    float bv = bias[((size_t)j * NW + i) * NI + e];
    for (int b = 0; b < BB; ++b) {
        float acc = bv;
#pragma unroll
        for (int d = 0; d < DH; ++d) acc += w[d] * xs[b][d];
        u[(((size_t)b * NJ + j) * NW + i) * NI + e] = acc;
    }
}

// beta[b,j,i] = dot_e(u[b,j,i,:], v[b,i,:]); b_log (+)= beta; c = softmax_i(b_log)
// one block per (b,j)
__global__ void k_beta(const float* __restrict__ u, const float* __restrict__ v,
                       float* __restrict__ b_log, float* __restrict__ c, int accflag) {
    int b = blockIdx.x >> 8;
    int j = blockIdx.x & 255;
    int tid = threadIdx.x;
    int lane = tid & 63, wave = tid >> 6;
    const float* up = u + ((size_t)b * NJ + j) * NW * NI;
    const float* vp = v + (size_t)b * NW * NI;
    __shared__ float red[NW][4];
    for (int row = 0; row < NW; ++row) {
        float p = up[(size_t)row * NI + tid] * vp[(size_t)row * NI + tid];
#pragma unroll
        for (int off = 32; off >= 1; off >>= 1) p += __shfl_down(p, off);
        if (lane == 0) red[row][wave] = p;
    }
    __syncthreads();
    if (tid < NW) {
        float bta = red[tid][0] + red[tid][1] + red[tid][2] + red[tid][3];
        size_t bidx = ((size_t)b * NJ + j) * NW + tid;
        if (accflag) bta += b_log[bidx];
        b_log[bidx] = bta;
        // softmax over the 32 lanes (all within wave 0)
        float m = bta;
#pragma unroll
        for (int mask = 16; mask >= 1; mask >>= 1) m = fmaxf(m, __shfl_xor(m, mask));
        float ex = __expf(bta - m);
        float s = ex;
#pragma unroll
        for (int mask = 16; mask >= 1; mask >>= 1) s += __shfl_xor(s, mask);
        c[bidx] = ex / s;
    }
}

// s[b,i,e] = sum_j c[b,j,i] * u[b,j,i,e]  (uniform: c = 1/NW); v = squash(s)
// one block per (b,i); thread = e
__global__ void k_sum_squash(const float* __restrict__ u, const float* __restrict__ c,
                             float* __restrict__ v, int uniform) {
    int b = blockIdx.x >> 5;
    int i = blockIdx.x & 31;
    int tid = threadIdx.x;
    int lane = tid & 63, wave = tid >> 6;
    __shared__ float cs[NJ];
    __shared__ float red[4];
    if (uniform) cs[tid] = 1.0f / NW;
    else         cs[tid] = c[((size_t)b * NJ + tid) * NW + i];
    __syncthreads();
    float acc = 0.f;
    const float* up = u + ((size_t)b * NJ * NW + i) * NI + tid;
#pragma unroll 4
    for (int j = 0; j < NJ; ++j) acc += cs[j] * up[(size_t)j * NW * NI];
    float p = acc * acc;
#pragma unroll
    for (int off = 32; off >= 1; off >>= 1) p += __shfl_down(p, off);
    if (lane == 0) red[wave] = p;
    __syncthreads();
    float n2 = red[0] + red[1] + red[2] + red[3];
    float n = sqrtf(n2);
    float f = n / (1.0f + n2);
    v[((size_t)b * NW + i) * NI + tid] = f * acc;
}

// out = v @ Wo^T + bo
__global__ void k_proj_out(const float* __restrict__ v, const float* __restrict__ Wo,
                           const float* __restrict__ bo, float* __restrict__ out) {
    int row = blockIdx.x;          // b*NW + i
    int k = threadIdx.x;
    __shared__ float vr[NI];
    vr[k] = v[(size_t)row * NI + k];
    __syncthreads();
    const float4* wo  = (const float4*)(Wo + (size_t)k * NI);
    const float4* vr4 = (const float4*)vr;
    float acc = bo[k];
#pragma unroll 8
    for (int m = 0; m < NI / 4; ++m) {
        float4 w = wo[m]; float4 xv = vr4[m];
        acc += w.x * xv.x + w.y * xv.y + w.z * xv.z + w.w * xv.w;
    }
    out[(size_t)row * DIMM + k] = acc;
}

extern "C" void kernel_launch(void* const* d_in, const int* in_sizes, int n_in,
                              void* d_out, int out_size, void* d_ws, size_t ws_size,
                              hipStream_t stream) {
    const float* x    = (const float*)d_in[0];
    const float* W    = (const float*)d_in[1];
    const float* bias = (const float*)d_in[2];
    const float* Wi   = (const float*)d_in[3];
    const float* bi   = (const float*)d_in[4];
    const float* Wo   = (const float*)d_in[5];
    const float* bo   = (const float*)d_in[6];
    float* out = (float*)d_out;

    float* ws    = (float*)d_ws;
    float* xh    = ws;                      // 131072 floats
    float* u     = ws + 131072;             // 33554432 floats (134 MB)
    float* b_log = u + 33554432;            // 131072
    float* c     = b_log + 131072;          // 131072
    float* v     = c + 131072;              // 131072

    k_proj_in<<<dim3(BB * NW), dim3(256), 0, stream>>>(x, Wi, bi, xh);
    k_uhat<<<dim3(NJ * NW), dim3(256), 0, stream>>>(W, bias, xh, u);

    // iter 0: uniform c -> v0
    k_sum_squash<<<dim3(BB * NW), dim3(256), 0, stream>>>(u, nullptr, v, 1);
    // iter 1
    k_beta<<<dim3(BB * NJ), dim3(256), 0, stream>>>(u, v, b_log, c, 0);
    k_sum_squash<<<dim3(BB * NW), dim3(256), 0, stream>>>(u, c, v, 0);
    // iter 2
    k_beta<<<dim3(BB * NJ), dim3(256), 0, stream>>>(u, v, b_log, c, 1);
    k_sum_squash<<<dim3(BB * NW), dim3(256), 0, stream>>>(u, c, v, 0);

    k_proj_out<<<dim3(BB * NW), dim3(256), 0, stream>>>(v, Wo, bo, out);
}